// Round 7
// baseline (614.450 us; speedup 1.0000x reference)
//
#include <hip/hip_runtime.h>

typedef unsigned short u16;
typedef unsigned int u32;

#define Bb 2
#define Lc 2048
#define Dc 2048
#define Hc 16
#define DhC 128

typedef __bf16 bf16x8 __attribute__((ext_vector_type(8)));
typedef float f32x4 __attribute__((ext_vector_type(4)));

__device__ __forceinline__ u16 f2b(float f) {
  u32 u = __float_as_uint(f);
  u32 r = (u + 0x7fffu + ((u >> 16) & 1u)) >> 16;
  return (u16)r;
}
__device__ __forceinline__ float b2f(u16 u) {
  return __uint_as_float(((u32)u) << 16);
}

// async global->LDS DMA, 16B/lane; LDS dest = wave-uniform base + lane*16
__device__ __forceinline__ void gll16(const void* g, void* l) {
  __builtin_amdgcn_global_load_lds(
      (const __attribute__((address_space(1))) u32*)g,
      (__attribute__((address_space(3))) u32*)l, 16, 0, 0);
}

// ---------------------------------------------------------------------------
// Dtype sniffer + x canonicalize (safety; ~15us total).
// ---------------------------------------------------------------------------
__global__ __launch_bounds__(256) void sniff_dtype(const u16* __restrict__ x,
                                                   int* __restrict__ flag) {
  __shared__ int bad;
  if (threadIdx.x == 0) bad = 0;
  __syncthreads();
  int local = 0;
  for (int i = threadIdx.x; i < 65536; i += 256) {
    float v = fabsf(b2f(x[i]));
    if (!(v < 1000.f)) local = 1;
  }
  if (local) atomicOr(&bad, 1);
  __syncthreads();
  if (threadIdx.x == 0) *flag = bad;
}

__global__ __launch_bounds__(256) void conv_x(const void* __restrict__ in,
                                              u16* __restrict__ out,
                                              const int* __restrict__ flag) {
  const int f32 = *flag;
  const int i0 = (blockIdx.x * 256 + threadIdx.x) * 4;
  if (f32) {
    const float* p = (const float*)in;
#pragma unroll
    for (int j = 0; j < 4; j++) out[i0 + j] = f2b(p[i0 + j]);
  } else {
    const u16* p = (const u16*)in;
#pragma unroll
    for (int j = 0; j < 4; j++) out[i0 + j] = p[i0 + j];
  }
}

// ---------------------------------------------------------------------------
// 2048x2048 transpose with dtype conversion (weights -> bf16 W^T).
// ---------------------------------------------------------------------------
__global__ __launch_bounds__(256) void transpose2d_conv(const void* __restrict__ in,
                                                        u16* __restrict__ out,
                                                        const int* __restrict__ flag) {
  __shared__ __align__(16) u16 tile[64][65];
  const int f32 = *flag;
  const int r0 = blockIdx.y * 64, c0 = blockIdx.x * 64;
  const int tc = threadIdx.x & 63, tr4 = threadIdx.x >> 6;
#pragma unroll
  for (int p = 0; p < 16; p++) {
    int r = tr4 + p * 4;
    size_t idx = (size_t)(r0 + r) * 2048 + c0 + tc;
    tile[r][tc] = f32 ? f2b(((const float*)in)[idx]) : ((const u16*)in)[idx];
  }
  __syncthreads();
#pragma unroll
  for (int p = 0; p < 16; p++) {
    int rr = tr4 + p * 4;
    out[(size_t)(c0 + rr) * 2048 + r0 + tc] = tile[tc][rr];
  }
}

// ---------------------------------------------------------------------------
// Shared GEMM K-loop body (m97 structure + XOR-swizzled LDS, r6-verified).
// A[m0..m0+128) x BtB rows [0..128) over K=2048 -> acc[4][4].
// ---------------------------------------------------------------------------
__device__ __forceinline__ void gemm_kloop(const u16* __restrict__ A, int m0,
                                           const u16* __restrict__ BtB,
                                           u16* As, u16* Bs, f32x4 (*acc)[4]) {
  constexpr int K = 2048;
  const int tid = threadIdx.x;
  const int lane = tid & 63, wid = tid >> 6;
  const int wm = (wid >> 1) * 64, wn = (wid & 1) * 64;
  const int quad = lane >> 4, l15 = lane & 15;
  const int sw = l15 & 7;
  const int srl = (lane >> 3), ssl = lane & 7;

  for (int k0 = 0; k0 < K; k0 += 64) {
#pragma unroll
    for (int p = 0; p < 4; p++) {
      const int r = p * 32 + wid * 8 + srl;
      const int c = ssl ^ (r & 7);
      gll16(A + (size_t)(m0 + r) * K + k0 + c * 8, As + (p * 256 + wid * 64) * 8);
    }
#pragma unroll
    for (int p = 0; p < 4; p++) {
      const int r = p * 32 + wid * 8 + srl;
      const int c = ssl ^ (r & 7);
      gll16(BtB + (size_t)r * K + k0 + c * 8, Bs + (p * 256 + wid * 64) * 8);
    }
    __syncthreads();
#pragma unroll
    for (int ks = 0; ks < 2; ks++) {
      bf16x8 af[4], bfr[4];
#pragma unroll
      for (int t = 0; t < 4; t++) {
        const int cc = ((ks * 4 + quad) ^ sw) * 8;
        af[t]  = *(const bf16x8*)(&As[(wm + t * 16 + l15) * 64 + cc]);
        bfr[t] = *(const bf16x8*)(&Bs[(wn + t * 16 + l15) * 64 + cc]);
      }
#pragma unroll
      for (int mt = 0; mt < 4; mt++)
#pragma unroll
        for (int nt = 0; nt < 4; nt++)
          acc[mt][nt] = __builtin_amdgcn_mfma_f32_16x16x32_bf16(af[mt], bfr[nt], acc[mt][nt], 0, 0, 0);
    }
    __syncthreads();
  }
}

// ---------------------------------------------------------------------------
// Fused QKV GEMM: A[4096,2048] @ WTall[6144,2048]^T -> Qo/Ko/Vo [4096,2048].
// Grid (32, 48): 1536 blocks (6/CU capacity) vs 3x512 before.
// ---------------------------------------------------------------------------
__global__ __launch_bounds__(256) void gemm_qkv(const u16* __restrict__ A,
                                                const u16* __restrict__ WTall,
                                                u16* __restrict__ Qo,
                                                u16* __restrict__ Ko,
                                                u16* __restrict__ Vo) {
  __shared__ __align__(16) u16 As[128 * 64];
  __shared__ __align__(16) u16 Bs[128 * 64];
  const int m0 = blockIdx.x * 128;
  const int n0g = blockIdx.y * 128;
  u16* Co = (n0g < 2048) ? Qo : (n0g < 4096) ? Ko : Vo;
  const int n0 = n0g & 2047;

  const f32x4 fz = {0.f, 0.f, 0.f, 0.f};
  f32x4 acc[4][4];
#pragma unroll
  for (int i = 0; i < 4; i++)
#pragma unroll
    for (int j = 0; j < 4; j++) acc[i][j] = fz;

  gemm_kloop(A, m0, WTall + (size_t)n0g * 2048, As, Bs, acc);

  const int lane = threadIdx.x & 63, wid = threadIdx.x >> 6;
  const int wm = (wid >> 1) * 64, wn = (wid & 1) * 64;
  const int quad = lane >> 4, l15 = lane & 15;
#pragma unroll
  for (int mt = 0; mt < 4; mt++)
#pragma unroll
    for (int nt = 0; nt < 4; nt++) {
      int col = n0 + wn + nt * 16 + l15;
#pragma unroll
      for (int r = 0; r < 4; r++) {
        int row = m0 + wm + mt * 16 + quad * 4 + r;
        Co[(size_t)row * 2048 + col] = f2b(acc[mt][nt][r]);
      }
    }
}

// ---------------------------------------------------------------------------
// Final GEMM: Ob @ WoT^T -> fp32 out.
// ---------------------------------------------------------------------------
__global__ __launch_bounds__(256) void gemm_bt_f32(const u16* __restrict__ A,
                                                   const u16* __restrict__ Bt,
                                                   float* __restrict__ C) {
  __shared__ __align__(16) u16 As[128 * 64];
  __shared__ __align__(16) u16 Bs[128 * 64];
  const int m0 = blockIdx.x * 128, n0 = blockIdx.y * 128;

  const f32x4 fz = {0.f, 0.f, 0.f, 0.f};
  f32x4 acc[4][4];
#pragma unroll
  for (int i = 0; i < 4; i++)
#pragma unroll
    for (int j = 0; j < 4; j++) acc[i][j] = fz;

  gemm_kloop(A, m0, Bt + (size_t)n0 * 2048, As, Bs, acc);

  const int lane = threadIdx.x & 63, wid = threadIdx.x >> 6;
  const int wm = (wid >> 1) * 64, wn = (wid & 1) * 64;
  const int quad = lane >> 4, l15 = lane & 15;
#pragma unroll
  for (int mt = 0; mt < 4; mt++)
#pragma unroll
    for (int nt = 0; nt < 4; nt++) {
      int col = n0 + wn + nt * 16 + l15;
#pragma unroll
      for (int r = 0; r < 4; r++) {
        int row = m0 + wm + mt * 16 + quad * 4 + r;
        C[(size_t)row * 2048 + col] = acc[mt][nt][r];
      }
    }
}

// ---------------------------------------------------------------------------
// V (B,L,H,Dh) -> Vt (B,H,Dh,L)
// ---------------------------------------------------------------------------
__global__ __launch_bounds__(256) void transpose_v_k(const u16* __restrict__ V,
                                                     u16* __restrict__ Vt) {
  __shared__ __align__(16) u16 tile[64][65];
  const int z = blockIdx.z;
  const int b = z >> 4, h = z & 15;
  const int l0 = blockIdx.y * 64, d0 = blockIdx.x * 64;
  const int tc = threadIdx.x & 63, tr4 = threadIdx.x >> 6;
#pragma unroll
  for (int p = 0; p < 16; p++) {
    int l = tr4 + p * 4;
    tile[l][tc] = V[(size_t)((b * Lc + l0 + l) * Hc + h) * DhC + d0 + tc];
  }
  __syncthreads();
#pragma unroll
  for (int p = 0; p < 16; p++) {
    int dd = tr4 + p * 4;
    Vt[((size_t)z * DhC + d0 + dd) * Lc + l0 + tc] = tile[tc][dd];
  }
}

// ---------------------------------------------------------------------------
// RoPE in place; Q scaled by log2(e)/sqrt(Dh) so flash can use native exp2.
// ---------------------------------------------------------------------------
__global__ __launch_bounds__(256) void rope_qk(u16* __restrict__ Q, u16* __restrict__ K) {
  const int idx = blockIdx.x * 256 + threadIdx.x;
  const int j = idx & 63;
  const int l = (idx >> 10) & 2047;
  const float inv = expf(-0.2050369278f * (float)j);  // theta^(-j/64)
  const float ang = (float)l * inv;
  float s, c;
  sincosf(ang, &s, &c);
  const size_t off = (size_t)idx * 2;
  const float q0 = b2f(Q[off]), q1 = b2f(Q[off + 1]);
  const float k0 = b2f(K[off]), k1 = b2f(K[off + 1]);
  const float sc = 0.1275187487f;  // (1/sqrt(128)) * log2(e)
  Q[off]     = f2b((q0 * c - q1 * s) * sc);
  Q[off + 1] = f2b((q1 * c + q0 * s) * sc);
  K[off]     = f2b(k0 * c - k1 * s);
  K[off + 1] = f2b(k1 * c + k0 * s);
}

// ---------------------------------------------------------------------------
// Flash attention (causal). r7 vs r6 (177us, Occ 11.7%, VALUBusy 25%):
//  - KV tile 32, LDS 38KB -> 4 blocks/CU (2x resident waves for latency hide)
//  - psum via MFMA against constant all-ones B-frag (kills the 4-step
//    ds_bpermute sum tree + 16 VALU per tile; l accumulated in C-layout)
//  - exp2-domain softmax (log2e folded into Q scale): native v_exp_f32
//  - DMA double-buffer + XOR swizzle + LPT + single barrier/tile kept from r6
// ---------------------------------------------------------------------------
#define NEGBIG (-3.0e30f)
__global__ __launch_bounds__(256) void flash_attn(const u16* __restrict__ Q,
                                                  const u16* __restrict__ Kg,
                                                  const u16* __restrict__ Vt,
                                                  u16* __restrict__ O) {
  __shared__ __align__(16) u16 Ks[2][32 * 128];  // [kv=32][Dh=128], 8KB each
  __shared__ __align__(16) u16 Vs[2][128 * 32];  // [d=128][kv=32], 8KB each
  __shared__ __align__(16) u16 Ps[4][16][40];    // per-wave P, +8 pad
  const int tid = threadIdx.x;
  const int lane = tid & 63, w = tid >> 6;
  const int quad = lane >> 4, l15 = lane & 15;
  const int qt = (int)gridDim.x - 1 - (int)blockIdx.x;  // heavy first (LPT)
  const int bh = blockIdx.y;
  const int b = bh >> 4, h = bh & 15;
  const int q0 = qt * 64;
  const int qrow = q0 + w * 16 + l15;

  bf16x8 aq[4];
  const u16* qptr = Q + ((size_t)(b * Lc + qrow) * Hc + h) * DhC + quad * 8;
#pragma unroll
  for (int ks = 0; ks < 4; ks++) aq[ks] = *(const bf16x8*)(qptr + ks * 32);

  // constant all-ones B-fragment for the row-sum MFMA
  bf16x8 one8;
#pragma unroll
  for (int j = 0; j < 8; j++) one8[j] = (__bf16)1.0f;

  // DMA staging maps. K: physical chunk p*256+w*64+lane -> row p*16+w*4+(lane>>4),
  // slot lane&15, global chunk slot^(row&15). V: row p*64+w*16+(lane>>2),
  // slot lane&3, global chunk slot^((row>>2)&3) = (lane&3)^(lane>>4).
  const int k_r = w * 4 + (lane >> 4);        // + p*16
  const int k_gc = (lane & 15) ^ k_r;         // row&15 == k_r (p*16 drops)
  const int v_r = w * 16 + (lane >> 2);       // + p*64
  const int v_gc = (lane & 3) ^ (lane >> 4);  // slot ^ (row>>2)&3

#define STAGE_KV(kv0, buf)                                                        \
  {                                                                               \
    _Pragma("unroll") for (int p = 0; p < 2; p++)                                 \
        gll16(Kg + ((size_t)(b * Lc + (kv0) + p * 16 + k_r) * Hc + h) * DhC +     \
                  k_gc * 8,                                                       \
              &Ks[buf][(p * 256 + w * 64) * 8]);                                  \
    _Pragma("unroll") for (int p = 0; p < 2; p++)                                 \
        gll16(Vt + ((size_t)bh * DhC + p * 64 + v_r) * Lc + (kv0) + v_gc * 8,     \
              &Vs[buf][(p * 256 + w * 64) * 8]);                                  \
  }

  STAGE_KV(0, 0);

  const f32x4 fz = {0.f, 0.f, 0.f, 0.f};
  f32x4 o[8];
#pragma unroll
  for (int f = 0; f < 8; f++) o[f] = fz;
  f32x4 psacc = fz;  // row-sum accumulator (l), C-layout
  float mrow[4];
#pragma unroll
  for (int r = 0; r < 4; r++) mrow[r] = NEGBIG;

  __syncthreads();  // tile 0 DMA complete

  const int ntiles = 2 * qt + 2;
  for (int kvt = 0; kvt < ntiles; kvt++) {
    const int cur = kvt & 1;
    const u16* Ksc = Ks[cur];
    const u16* Vsc = Vs[cur];

    if (kvt + 1 < ntiles) STAGE_KV((kvt + 1) * 32, cur ^ 1);

    // S = Q @ K^T : 2 col-tiles of 16 kv
    f32x4 s[2] = {fz, fz};
#pragma unroll
    for (int ks = 0; ks < 4; ks++) {
#pragma unroll
      for (int ct = 0; ct < 2; ct++) {
        bf16x8 bk = *(const bf16x8*)(
            &Ksc[(ct * 16 + l15) * 128 + (((ks << 2) + quad) ^ l15) * 8]);
        s[ct] = __builtin_amdgcn_mfma_f32_16x16x32_bf16(aq[ks], bk, s[ct], 0, 0, 0);
      }
    }

    // causal mask (only the last two tiles can straddle the diagonal)
    if (kvt >= 2 * qt) {
      const int kv0 = kvt * 32;
#pragma unroll
      for (int ct = 0; ct < 2; ct++) {
        int kvc = kv0 + ct * 16 + l15;
#pragma unroll
        for (int r = 0; r < 4; r++) {
          int qr = q0 + w * 16 + quad * 4 + r;
          if (kvc > qr) s[ct][r] = NEGBIG;
        }
      }
    }

    // online softmax in log2 domain; max over row's 16 lanes
    float mnew[4], alpha[4];
#pragma unroll
    for (int r = 0; r < 4; r++) {
      float mx = fmaxf(s[0][r], s[1][r]);
#pragma unroll
      for (int off = 1; off < 16; off <<= 1) mx = fmaxf(mx, __shfl_xor(mx, off, 64));
      mnew[r] = fmaxf(mrow[r], mx);
      alpha[r] = exp2f(mrow[r] - mnew[r]);
      mrow[r] = mnew[r];
    }
#pragma unroll
    for (int ct = 0; ct < 2; ct++)
#pragma unroll
      for (int r = 0; r < 4; r++) s[ct][r] = exp2f(s[ct][r] - mnew[r]);
#pragma unroll
    for (int f = 0; f < 8; f++)
#pragma unroll
      for (int r = 0; r < 4; r++) o[f][r] *= alpha[r];
#pragma unroll
    for (int r = 0; r < 4; r++) psacc[r] *= alpha[r];

    // P: C-layout -> LDS (wave-private, no barrier) -> A-frag
#pragma unroll
    for (int ct = 0; ct < 2; ct++)
#pragma unroll
      for (int r = 0; r < 4; r++)
        Ps[w][quad * 4 + r][ct * 16 + l15] = f2b(s[ct][r]);
    bf16x8 ap = *(const bf16x8*)(&Ps[w][l15][quad * 8]);

    // O += P @ V ; l += P @ 1 (single extra MFMA replaces the sum tree)
#pragma unroll
    for (int f = 0; f < 8; f++) {
      bf16x8 bv = *(const bf16x8*)(
          &Vsc[(f * 16 + l15) * 32 + (quad ^ ((l15 >> 2) & 3)) * 8]);
      o[f] = __builtin_amdgcn_mfma_f32_16x16x32_bf16(ap, bv, o[f], 0, 0, 0);
    }
    psacc = __builtin_amdgcn_mfma_f32_16x16x32_bf16(ap, one8, psacc, 0, 0, 0);

    __syncthreads();  // all waves done with buf(cur); prefetch DMA drained
  }

#pragma unroll
  for (int f = 0; f < 8; f++) {
    int d = f * 16 + l15;
#pragma unroll
    for (int r = 0; r < 4; r++) {
      int qr = q0 + w * 16 + quad * 4 + r;
      O[((size_t)(b * Lc + qr) * Hc + h) * DhC + d] = f2b(o[f][r] / psacc[r]);
    }
  }
}

// ---------------------------------------------------------------------------
// ws layout (~101 MiB; ws_size >= 151 MiB proven in r3):
//   flag 256B | WTall 3x8.4MB | WoT 8.4MB | xc 16.8 | Qb 16.8 | Kb 16.8 | Vb 16.8
//   Vtb aliases xc (dead after QKV gemm); Ob aliases Vb (dead after v-transpose)
// ---------------------------------------------------------------------------
extern "C" void kernel_launch(void* const* d_in, const int* in_sizes, int n_in,
                              void* d_out, int out_size, void* d_ws, size_t ws_size,
                              hipStream_t stream) {
  const void* x  = d_in[0];
  const void* Wq = d_in[1];
  const void* Wk = d_in[2];
  const void* Wv = d_in[3];
  const void* Wo = d_in[4];
  float* out = (float*)d_out;

  char* w = (char*)d_ws;
  const size_t WSZ = (size_t)2048 * 2048;
  const size_t XSZ = (size_t)Bb * Lc * Dc;
  int* flag = (int*)w;
  u16* WTall = (u16*)(w + 256);
  u16* WoT = WTall + 3 * WSZ;
  u16* xc  = WoT + WSZ;
  u16* Qb  = xc + XSZ;
  u16* Kb  = Qb + XSZ;
  u16* Vb  = Kb + XSZ;
  u16* Vtb = xc;
  u16* Ob  = Vb;

  sniff_dtype<<<1, 256, 0, stream>>>((const u16*)x, flag);
  conv_x<<<(int)(XSZ / 1024), 256, 0, stream>>>(x, xc, flag);

  dim3 tgrid(32, 32);
  transpose2d_conv<<<tgrid, 256, 0, stream>>>(Wq, WTall, flag);
  transpose2d_conv<<<tgrid, 256, 0, stream>>>(Wk, WTall + WSZ, flag);
  transpose2d_conv<<<tgrid, 256, 0, stream>>>(Wv, WTall + 2 * WSZ, flag);
  transpose2d_conv<<<tgrid, 256, 0, stream>>>(Wo, WoT, flag);

  dim3 qkvgrid(32, 48);
  gemm_qkv<<<qkvgrid, 256, 0, stream>>>(xc, WTall, Qb, Kb, Vb);

  rope_qk<<<(Bb * Lc * Hc * 64) / 256, 256, 0, stream>>>(Qb, Kb);

  dim3 vgrid(2, 32, 32);
  transpose_v_k<<<vgrid, 256, 0, stream>>>(Vb, Vtb);

  dim3 fgrid(32, 32);
  flash_attn<<<fgrid, 256, 0, stream>>>(Qb, Kb, Vtb, Ob);

  dim3 ogrid(32, 16);
  gemm_bt_f32<<<ogrid, 256, 0, stream>>>(Ob, WoT, out);
}